// Round 6
// baseline (256.950 us; speedup 1.0000x reference)
//
#include <hip/hip_runtime.h>
#include <math.h>

// ---------------------------------------------------------------------------
// e3nn tensor product: 64x0e+64x1o+64x2e  (x)  1x0e+1x1o+1x2e -> 18 CG paths,
// output sorted-concat to 72 floats per (batch, channel u), 4608 per batch row.
//
// R6: DIAGNOSTIC round. Exact R5 structure, but the path/store phase executes
// REP (=3, runtime arg -> no dead-store elimination) times so tp_direct's
// per-dispatch duration exceeds the harness's 1.2GB fill kernels and finally
// surfaces in the rocprof top-5 with its own FETCH/WRITE/VALU/Occupancy/
// LDS-conflict counters. LDS is read-only in the repeated phase -> race-free,
// deterministic, output values unchanged. Next round interprets and reverts.
// ---------------------------------------------------------------------------

namespace {
constexpr int NP = 18;
constexpr int P_CH1[NP] = {0,0,0,1,1,1,1,1,1,1,2,2,2,2,2,2,2,2}; // l1
constexpr int P_CH2[NP] = {0,1,2,0,1,1,1,2,2,2,0,1,1,1,2,2,2,2}; // l2
constexpr int P_LO [NP] = {0,1,2,1,0,1,2,1,2,3,2,1,2,3,0,1,2,3};
// output column offset of each path's chunk (64*(2lo+1) wide), sorted order
constexpr int P_OUT[NP] = {0,192,1344,384,64,960,1664,576,2624,3264,
                           1984,768,2944,3712,128,1152,2304,4160};
// CG table offsets (floats), sizes (2l1+1)(2l2+1)(2lo+1)
constexpr int C_OFF[NP] = {0,1,10,35,44,53,80,125,170,245,350,375,420,495,600,625,700,825};
// M table offsets (floats), sizes (2l1+1)(2lo+1), layout per path [io][i1]
constexpr int M_OFF[NP] = {0,1,4,9,18,21,30,45,54,69,90,115,130,155,190,195,210,235};
constexpr int M_TOT = 270;
// input2 column offset per chunk
constexpr int X2_OFF[3] = {0,1,4};
// x1 row chunk base offsets (floats) per l1
constexpr int X1G[3] = {0,64,256};
}

// ------------------------- CG table construction (fp64) --------------------

struct cdbl { double re, im; };
__device__ inline cdbl cmul(cdbl a, cdbl b){
  return { a.re*b.re - a.im*b.im, a.re*b.im + a.im*b.re };
}

__device__ inline double dfact(int n){
  const double F[9] = {1.,1.,2.,6.,24.,120.,720.,5040.,40320.};
  return F[n];
}

__device__ double su2cg(int j1,int m1,int j2,int m2,int j3,int m3){
  if (m1 + m2 != m3) return 0.0;
  int vmin = max(max(-j1 + j2 + m3, -j1 + m1), 0);
  int vmax = min(min(j2 + j3 + m1, j3 - j1 + j2), j3 + m3);
  if (vmax < vmin) return 0.0;
  double C = sqrt((2.0*j3 + 1.0)
      * dfact(j3 + j1 - j2) * dfact(j3 - j1 + j2) * dfact(j1 + j2 - j3)
      * dfact(j3 + m3) * dfact(j3 - m3)
      / (dfact(j1 + j2 + j3 + 1) * dfact(j1 - m1) * dfact(j1 + m1)
         * dfact(j2 - m2) * dfact(j2 + m2)));
  double S = 0.0;
  for (int v = vmin; v <= vmax; ++v){
    double t = dfact(j2 + j3 + m1 - v) * dfact(j1 - m1 + v)
        / (dfact(v) * dfact(j3 - j1 + j2 - v) * dfact(j3 + m3 - v)
           * dfact(v + j1 - j2 - m3));
    S += (((v + j2 + m2) & 1) ? -t : t);
  }
  return C * S;
}

// change_basis_real_to_complex(l)[row][col], including the (-i)^l prefactor
__device__ cdbl Qval(int l, int row, int col){
  const double s2 = 0.70710678118654752440;
  int m = row - l;
  cdbl v = {0.0, 0.0};
  if (m < 0){
    if (col == l - m)       v = { s2, 0.0 };
    else if (col == l + m)  v = { 0.0, -s2 };
  } else if (m == 0){
    if (col == l)           v = { 1.0, 0.0 };
  } else {
    double sg = (m & 1) ? -1.0 : 1.0;
    if (col == l + m)       v = { sg*s2, 0.0 };
    else if (col == l - m)  v = { 0.0, sg*s2 };
  }
  cdbl ph;
  switch (l & 3){            // (-i)^l
    case 0: ph = { 1.0, 0.0 }; break;
    case 1: ph = { 0.0,-1.0 }; break;
    case 2: ph = {-1.0, 0.0 }; break;
    default: ph = { 0.0, 1.0 }; break;
  }
  return cmul(ph, v);
}

// one block per path; thread e computes real CG entry [a1][a2][a3]
__global__ __launch_bounds__(256) void cg_init(float* __restrict__ cg){
  int p = blockIdx.x;
  int l1 = P_CH1[p], l2 = P_CH2[p], l3 = P_LO[p];
  int n1 = 2*l1+1, n2 = 2*l2+1, n3 = 2*l3+1;
  int sz = n1*n2*n3;
  int e = threadIdx.x;
  if (e >= sz) return;
  int a1 = e / (n2*n3);
  int r  = e - a1*(n2*n3);
  int a2 = r / n3;
  int a3 = r - a2*n3;
  double acc = 0.0;
  for (int i = 0; i < n1; ++i){
    for (int k = 0; k < n2; ++k){
      int m1 = i - l1, m2 = k - l2, m3 = m1 + m2;
      if (m3 < -l3 || m3 > l3) continue;
      double a = su2cg(l1, m1, l2, m2, l3, m3);
      if (a == 0.0) continue;
      cdbl q1 = Qval(l1, i, a1);
      cdbl q2 = Qval(l2, k, a2);
      cdbl q3 = Qval(l3, l3 + m3, a3);
      q3.im = -q3.im;                      // conj (Q3.conj().T)
      cdbl t = cmul(cmul(q1, q2), q3);
      acc += t.re * a;                     // imag cancels (asserted in ref)
    }
  }
  cg[C_OFF[p] + e] = (float)acc;
}

// ------------------------- per-row M precompute -----------------------------
// M[b][e], e in [0,270): per path p, layout [io][i1]: M = sum_j cg[i1,j,io]*x2[b,j]
__global__ __launch_bounds__(256) void m_kernel(const float* __restrict__ x2,
    const float* __restrict__ cg, float* __restrict__ M, int batch){
  int t = blockIdx.x*256 + threadIdx.x;
  if (t >= batch * M_TOT) return;
  int b = t / M_TOT;
  int e = t - b * M_TOT;
  const float* x2b = x2 + (size_t)b * 9;
  float acc = 0.f;
  #pragma unroll
  for (int p = 0; p < NP; ++p){
    const int n1 = 2*P_CH1[p]+1, n2 = 2*P_CH2[p]+1, no = 2*P_LO[p]+1;
    const int sz = n1 * no;
    if (e >= M_OFF[p] && e < M_OFF[p] + sz){
      int idx = e - M_OFF[p];
      int io  = idx / n1;
      int i1  = idx - io * n1;
      float s = 0.f;
      for (int j = 0; j < n2; ++j)
        s = fmaf(cg[C_OFF[p] + (i1*n2 + j)*no + io], x2b[X2_OFF[P_CH2[p]] + j], s);
      acc = s;
    }
  }
  M[(size_t)b * M_TOT + e] = acc;
}

// ------------------------- main contraction (direct-indexed) ---------------

template<int P>
__device__ __forceinline__ void path_out(const float* __restrict__ xs,
                                         const float* __restrict__ ms,
                                         float* __restrict__ ob, int t){
  constexpr int l1 = P_CH1[P];
  constexpr int n1 = 2*l1+1;
  constexpr int no = 2*P_LO[P]+1;
  constexpr int XO = X1G[l1];
  #pragma unroll
  for (int k = 0; k < no; ++k){
    const int f  = 64*k + t;
    const int u  = f / no;          // magic-mul (constant no)
    const int io = f - u*no;
    float acc = 0.f;
    #pragma unroll
    for (int i1 = 0; i1 < n1; ++i1)
      acc = fmaf(xs[XO + u*n1 + i1], ms[M_OFF[P] + io*n1 + i1], acc);
    ob[P_OUT[P] + f] = acc;         // dense 256B store transactions
  }
}

// 256 threads = 4 waves = 4 rows; per-wave 848-float LDS region
// (576 x1 + 270 M + 2 pad). One barrier total, before any global store.
// DIAGNOSTIC: path phase repeated `rep` times (runtime arg -> not DCE-able);
// LDS is read-only there, so passes are identical & race-free.
__global__ __launch_bounds__(256) void tp_direct(const float* __restrict__ x1,
    const float* __restrict__ M, float* __restrict__ out, int batch, int rep){
  __shared__ __align__(16) float sh[4][848];
  const int t = threadIdx.x & 63;
  int b = blockIdx.x * 4 + (threadIdx.x >> 6);
  if (b >= batch) b = batch - 1;            // uniform clamp; benign duplicate
  b = __builtin_amdgcn_readfirstlane(b);
  float* xs = sh[threadIdx.x >> 6];
  float* ms = xs + 576;

  // stage x1 row (144 float4, coalesced)
  const float4* xr4 = (const float4*)(x1 + (size_t)b * 576);
  float4* xs4 = (float4*)xs;
  xs4[t]      = xr4[t];
  xs4[t + 64] = xr4[t + 64];
  if (t < 16) xs4[t + 128] = xr4[t + 128];

  // stage M row (270 floats, coalesced)
  const float* Mb = M + (size_t)b * M_TOT;
  ms[t]       = Mb[t];
  ms[t + 64]  = Mb[t + 64];
  ms[t + 128] = Mb[t + 128];
  ms[t + 192] = Mb[t + 192];
  if (t < 14) ms[t + 256] = Mb[t + 256];

  __syncthreads();   // ONLY barrier; LDS read-only below, stores free-flow

  float* ob = out + (size_t)b * 4608;
  #pragma unroll 1
  for (int r = 0; r < rep; ++r){
    path_out< 0>(xs, ms, ob, t);
    path_out< 1>(xs, ms, ob, t);
    path_out< 2>(xs, ms, ob, t);
    path_out< 3>(xs, ms, ob, t);
    path_out< 4>(xs, ms, ob, t);
    path_out< 5>(xs, ms, ob, t);
    path_out< 6>(xs, ms, ob, t);
    path_out< 7>(xs, ms, ob, t);
    path_out< 8>(xs, ms, ob, t);
    path_out< 9>(xs, ms, ob, t);
    path_out<10>(xs, ms, ob, t);
    path_out<11>(xs, ms, ob, t);
    path_out<12>(xs, ms, ob, t);
    path_out<13>(xs, ms, ob, t);
    path_out<14>(xs, ms, ob, t);
    path_out<15>(xs, ms, ob, t);
    path_out<16>(xs, ms, ob, t);
    path_out<17>(xs, ms, ob, t);
  }
}

// fallback if d_ws is too small for the M table (proven R3 path)
__global__ __launch_bounds__(64) void tp_fallback(const float* __restrict__ x1,
    const float* __restrict__ x2, const float* __restrict__ cg,
    float* __restrict__ out){
  const int b = blockIdx.x;
  const int u = threadIdx.x;
  const float* xr = x1 + (size_t)b * 576;
  float xall[9];
  xall[0] = xr[u];
  #pragma unroll
  for (int i = 0; i < 3; ++i) xall[1+i] = xr[64 + u*3 + i];
  #pragma unroll
  for (int i = 0; i < 5; ++i) xall[4+i] = xr[256 + u*5 + i];
  const float* x2b = x2 + (size_t)b * 9;
  float x2v[9];
  #pragma unroll
  for (int j = 0; j < 9; ++j) x2v[j] = x2b[j];
  float* ob = out + (size_t)b * 4608;
  #pragma unroll
  for (int p = 0; p < NP; ++p){
    const int l1 = P_CH1[p];
    const int n1 = 2*l1+1;
    const int n2 = 2*P_CH2[p]+1;
    const int no = 2*P_LO[p]+1;
    const int X1O = (l1 == 0) ? 0 : (l1 == 1 ? 1 : 4);
    #pragma unroll
    for (int io = 0; io < no; ++io){
      float acc = 0.f;
      #pragma unroll
      for (int i1 = 0; i1 < n1; ++i1){
        float m = 0.f;
        #pragma unroll
        for (int j = 0; j < n2; ++j)
          m = fmaf(cg[C_OFF[p] + (i1*n2 + j)*no + io],
                   x2v[X2_OFF[P_CH2[p]] + j], m);
        acc = fmaf(xall[X1O + i1], m, acc);
      }
      ob[P_OUT[p] + u*no + io] = acc;
    }
  }
}

extern "C" void kernel_launch(void* const* d_in, const int* in_sizes, int n_in,
                              void* d_out, int out_size, void* d_ws, size_t ws_size,
                              hipStream_t stream){
  const float* x1 = (const float*)d_in[0];
  const float* x2 = (const float*)d_in[1];
  float* out = (float*)d_out;
  const int batch = in_sizes[0] / 576;

  float* cg = (float*)d_ws;                       // 1000 floats
  float* M  = (float*)((char*)d_ws + 4096);       // batch*270 floats
  const size_t need = 4096 + (size_t)batch * M_TOT * sizeof(float);

  cg_init<<<NP, 256, 0, stream>>>(cg);
  if (ws_size >= need){
    const int total = batch * M_TOT;
    m_kernel<<<(total + 255)/256, 256, 0, stream>>>(x2, cg, M, batch);
    tp_direct<<<(batch + 3)/4, 256, 0, stream>>>(x1, M, out, batch, /*rep=*/3);
  } else {
    tp_fallback<<<batch, 64, 0, stream>>>(x1, x2, cg, out);
  }
}

// Round 7
// 136.725 us; speedup vs baseline: 1.8793x; 1.8793x over previous
//
#include <hip/hip_runtime.h>
#include <math.h>

// ---------------------------------------------------------------------------
// e3nn tensor product: 64x0e+64x1o+64x2e  (x)  1x0e+1x1o+1x2e -> 18 CG paths,
// output sorted-concat to 72 floats per (batch, channel u), 4608 per batch row.
//
// R7: issue-bound fix (R6 diagnostic: 60us/pass with L2-hot writes, VALU 16%,
// HBM 40% -> per-CU DS/VMEM issue was the limiter; R5 burned ~3100 DS-pipe
// cyc/wave/pass reading both FMA operands from LDS).
//  - compute: lane = channel u, x1 in REGISTERS, M via wave-uniform global
//    pointer (scalar path) -> zero LDS reads in the FMA loop.
//  - per-path transpose bounce: 72 ds_write_b32 (odd stride, conflict-free) +
//    ~26 ds_read_b128 + ~26 global dwordx4 stores per wave -> ~750 DS cyc and
//    4x fewer store instrs than scalar-store variants.
//  - cross-lane bounce ordering: __builtin_amdgcn_wave_barrier() + asm memory
//    fence on both sides of the readback (R4's failure = compiler hoisting
//    cross-lane reads; HW DS is in-order per wave, only compiler order needed).
//    No s_barrier anywhere -> stores never drain mid-kernel.
//  - cg_init / m_kernel are the proven R1-R5 versions, unchanged.
// ---------------------------------------------------------------------------

namespace {
constexpr int NP = 18;
constexpr int P_CH1[NP] = {0,0,0,1,1,1,1,1,1,1,2,2,2,2,2,2,2,2}; // l1
constexpr int P_CH2[NP] = {0,1,2,0,1,1,1,2,2,2,0,1,1,1,2,2,2,2}; // l2
constexpr int P_LO [NP] = {0,1,2,1,0,1,2,1,2,3,2,1,2,3,0,1,2,3};
// output column offset of each path's chunk (64*(2lo+1) wide), sorted order
constexpr int P_OUT[NP] = {0,192,1344,384,64,960,1664,576,2624,3264,
                           1984,768,2944,3712,128,1152,2304,4160};
// CG table offsets (floats), sizes (2l1+1)(2l2+1)(2lo+1)
constexpr int C_OFF[NP] = {0,1,10,35,44,53,80,125,170,245,350,375,420,495,600,625,700,825};
// M table offsets (floats), sizes (2l1+1)(2lo+1), layout per path [io][i1]
constexpr int M_OFF[NP] = {0,1,4,9,18,21,30,45,54,69,90,115,130,155,190,195,210,235};
constexpr int M_TOT = 270;
// input2 column offset per chunk
constexpr int X2_OFF[3] = {0,1,4};
}

// ------------------------- CG table construction (fp64) --------------------

struct cdbl { double re, im; };
__device__ inline cdbl cmul(cdbl a, cdbl b){
  return { a.re*b.re - a.im*b.im, a.re*b.im + a.im*b.re };
}

__device__ inline double dfact(int n){
  const double F[9] = {1.,1.,2.,6.,24.,120.,720.,5040.,40320.};
  return F[n];
}

__device__ double su2cg(int j1,int m1,int j2,int m2,int j3,int m3){
  if (m1 + m2 != m3) return 0.0;
  int vmin = max(max(-j1 + j2 + m3, -j1 + m1), 0);
  int vmax = min(min(j2 + j3 + m1, j3 - j1 + j2), j3 + m3);
  if (vmax < vmin) return 0.0;
  double C = sqrt((2.0*j3 + 1.0)
      * dfact(j3 + j1 - j2) * dfact(j3 - j1 + j2) * dfact(j1 + j2 - j3)
      * dfact(j3 + m3) * dfact(j3 - m3)
      / (dfact(j1 + j2 + j3 + 1) * dfact(j1 - m1) * dfact(j1 + m1)
         * dfact(j2 - m2) * dfact(j2 + m2)));
  double S = 0.0;
  for (int v = vmin; v <= vmax; ++v){
    double t = dfact(j2 + j3 + m1 - v) * dfact(j1 - m1 + v)
        / (dfact(v) * dfact(j3 - j1 + j2 - v) * dfact(j3 + m3 - v)
           * dfact(v + j1 - j2 - m3));
    S += (((v + j2 + m2) & 1) ? -t : t);
  }
  return C * S;
}

// change_basis_real_to_complex(l)[row][col], including the (-i)^l prefactor
__device__ cdbl Qval(int l, int row, int col){
  const double s2 = 0.70710678118654752440;
  int m = row - l;
  cdbl v = {0.0, 0.0};
  if (m < 0){
    if (col == l - m)       v = { s2, 0.0 };
    else if (col == l + m)  v = { 0.0, -s2 };
  } else if (m == 0){
    if (col == l)           v = { 1.0, 0.0 };
  } else {
    double sg = (m & 1) ? -1.0 : 1.0;
    if (col == l + m)       v = { sg*s2, 0.0 };
    else if (col == l - m)  v = { 0.0, sg*s2 };
  }
  cdbl ph;
  switch (l & 3){            // (-i)^l
    case 0: ph = { 1.0, 0.0 }; break;
    case 1: ph = { 0.0,-1.0 }; break;
    case 2: ph = {-1.0, 0.0 }; break;
    default: ph = { 0.0, 1.0 }; break;
  }
  return cmul(ph, v);
}

// one block per path; thread e computes real CG entry [a1][a2][a3]
__global__ __launch_bounds__(256) void cg_init(float* __restrict__ cg){
  int p = blockIdx.x;
  int l1 = P_CH1[p], l2 = P_CH2[p], l3 = P_LO[p];
  int n1 = 2*l1+1, n2 = 2*l2+1, n3 = 2*l3+1;
  int sz = n1*n2*n3;
  int e = threadIdx.x;
  if (e >= sz) return;
  int a1 = e / (n2*n3);
  int r  = e - a1*(n2*n3);
  int a2 = r / n3;
  int a3 = r - a2*n3;
  double acc = 0.0;
  for (int i = 0; i < n1; ++i){
    for (int k = 0; k < n2; ++k){
      int m1 = i - l1, m2 = k - l2, m3 = m1 + m2;
      if (m3 < -l3 || m3 > l3) continue;
      double a = su2cg(l1, m1, l2, m2, l3, m3);
      if (a == 0.0) continue;
      cdbl q1 = Qval(l1, i, a1);
      cdbl q2 = Qval(l2, k, a2);
      cdbl q3 = Qval(l3, l3 + m3, a3);
      q3.im = -q3.im;                      // conj (Q3.conj().T)
      cdbl t = cmul(cmul(q1, q2), q3);
      acc += t.re * a;                     // imag cancels (asserted in ref)
    }
  }
  cg[C_OFF[p] + e] = (float)acc;
}

// ------------------------- per-row M precompute -----------------------------
// M[b][e], e in [0,270): per path p, layout [io][i1]: M = sum_j cg[i1,j,io]*x2[b,j]
__global__ __launch_bounds__(256) void m_kernel(const float* __restrict__ x2,
    const float* __restrict__ cg, float* __restrict__ M, int batch){
  int t = blockIdx.x*256 + threadIdx.x;
  if (t >= batch * M_TOT) return;
  int b = t / M_TOT;
  int e = t - b * M_TOT;
  const float* x2b = x2 + (size_t)b * 9;
  float acc = 0.f;
  #pragma unroll
  for (int p = 0; p < NP; ++p){
    const int n1 = 2*P_CH1[p]+1, n2 = 2*P_CH2[p]+1, no = 2*P_LO[p]+1;
    const int sz = n1 * no;
    if (e >= M_OFF[p] && e < M_OFF[p] + sz){
      int idx = e - M_OFF[p];
      int io  = idx / n1;
      int i1  = idx - io * n1;
      float s = 0.f;
      for (int j = 0; j < n2; ++j)
        s = fmaf(cg[C_OFF[p] + (i1*n2 + j)*no + io], x2b[X2_OFF[P_CH2[p]] + j], s);
      acc = s;
    }
  }
  M[(size_t)b * M_TOT + e] = acc;
}

// ------------------------- main contraction --------------------------------

template<int P>
__device__ __forceinline__ void do_path(const float xall[9],
                                        const float* __restrict__ Mb,  // uniform
                                        float* __restrict__ bbf,       // this wave's bounce
                                        float4* __restrict__ ob4, int t){
  constexpr int l1 = P_CH1[P];
  constexpr int n1 = 2*l1+1;
  constexpr int no = 2*P_LO[P]+1;
  constexpr int XO = (l1 == 0) ? 0 : (l1 == 1 ? 1 : 4);
  constexpr int B4 = P_OUT[P] >> 2;   // float4 base of this chunk
  constexpr int NF4 = 16*no;          // float4 count in this chunk

  // lane u computes its no outputs: x1 in regs, M wave-uniform (scalar path)
  #pragma unroll
  for (int io = 0; io < no; ++io){
    float acc = 0.f;
    #pragma unroll
    for (int i1 = 0; i1 < n1; ++i1)
      acc = fmaf(xall[XO + i1], Mb[M_OFF[P] + io*n1 + i1], acc);
    bbf[t*no + io] = acc;              // odd stride -> <=2 lanes/bank, free
  }
  // compiler fence: cross-lane LDS communication (HW DS is in-order per wave;
  // without this the compiler may hoist the reads -- R4's failure mode)
  __builtin_amdgcn_wave_barrier();
  asm volatile("" ::: "memory");

  const float4* bb4 = (const float4*)bbf;
  if constexpr (NF4 >= 64){
    ob4[B4 + t] = bb4[t];
    if constexpr (NF4 > 64){
      if (t < NF4 - 64) ob4[B4 + 64 + t] = bb4[64 + t];
    }
  } else {
    if (t < NF4) ob4[B4 + t] = bb4[t];
  }

  __builtin_amdgcn_wave_barrier();     // WAR: next path's writes stay after reads
  asm volatile("" ::: "memory");
}

// 256 threads = 4 waves = 4 rows, no __syncthreads (waves independent).
// Per-wave LDS: 456-float bounce region only.
__global__ __launch_bounds__(256) void tp_bounce(const float* __restrict__ x1,
    const float* __restrict__ M, float* __restrict__ out, int batch){
  __shared__ __align__(16) float bnc[4][456];
  const int t = threadIdx.x & 63;
  int b = blockIdx.x * 4 + (threadIdx.x >> 6);
  if (b >= batch) b = batch - 1;            // benign duplicate (batch%4==0 here)
  b = __builtin_amdgcn_readfirstlane(b);
  float* bbf = bnc[threadIdx.x >> 6];

  // x1 channel values straight to registers (lines fully consumed by the wave)
  const float* xr = x1 + (size_t)b * 576;
  float xall[9];
  xall[0] = xr[t];
  xall[1] = xr[64 + 3*t]; xall[2] = xr[65 + 3*t]; xall[3] = xr[66 + 3*t];
  #pragma unroll
  for (int i = 0; i < 5; ++i) xall[4+i] = xr[256 + 5*t + i];

  const float* Mb = M + (size_t)b * M_TOT;   // wave-uniform -> scalar loads
  float4* ob4 = (float4*)(out + (size_t)b * 4608);

  do_path< 0>(xall, Mb, bbf, ob4, t);
  do_path< 1>(xall, Mb, bbf, ob4, t);
  do_path< 2>(xall, Mb, bbf, ob4, t);
  do_path< 3>(xall, Mb, bbf, ob4, t);
  do_path< 4>(xall, Mb, bbf, ob4, t);
  do_path< 5>(xall, Mb, bbf, ob4, t);
  do_path< 6>(xall, Mb, bbf, ob4, t);
  do_path< 7>(xall, Mb, bbf, ob4, t);
  do_path< 8>(xall, Mb, bbf, ob4, t);
  do_path< 9>(xall, Mb, bbf, ob4, t);
  do_path<10>(xall, Mb, bbf, ob4, t);
  do_path<11>(xall, Mb, bbf, ob4, t);
  do_path<12>(xall, Mb, bbf, ob4, t);
  do_path<13>(xall, Mb, bbf, ob4, t);
  do_path<14>(xall, Mb, bbf, ob4, t);
  do_path<15>(xall, Mb, bbf, ob4, t);
  do_path<16>(xall, Mb, bbf, ob4, t);
  do_path<17>(xall, Mb, bbf, ob4, t);
}

// fallback if d_ws is too small for the M table (proven path)
__global__ __launch_bounds__(64) void tp_fallback(const float* __restrict__ x1,
    const float* __restrict__ x2, const float* __restrict__ cg,
    float* __restrict__ out){
  const int b = blockIdx.x;
  const int u = threadIdx.x;
  const float* xr = x1 + (size_t)b * 576;
  float xall[9];
  xall[0] = xr[u];
  #pragma unroll
  for (int i = 0; i < 3; ++i) xall[1+i] = xr[64 + u*3 + i];
  #pragma unroll
  for (int i = 0; i < 5; ++i) xall[4+i] = xr[256 + u*5 + i];
  const float* x2b = x2 + (size_t)b * 9;
  float x2v[9];
  #pragma unroll
  for (int j = 0; j < 9; ++j) x2v[j] = x2b[j];
  float* ob = out + (size_t)b * 4608;
  #pragma unroll
  for (int p = 0; p < NP; ++p){
    const int l1 = P_CH1[p];
    const int n1 = 2*l1+1;
    const int n2 = 2*P_CH2[p]+1;
    const int no = 2*P_LO[p]+1;
    const int X1O = (l1 == 0) ? 0 : (l1 == 1 ? 1 : 4);
    #pragma unroll
    for (int io = 0; io < no; ++io){
      float acc = 0.f;
      #pragma unroll
      for (int i1 = 0; i1 < n1; ++i1){
        float m = 0.f;
        #pragma unroll
        for (int j = 0; j < n2; ++j)
          m = fmaf(cg[C_OFF[p] + (i1*n2 + j)*no + io],
                   x2v[X2_OFF[P_CH2[p]] + j], m);
        acc = fmaf(xall[X1O + i1], m, acc);
      }
      ob[P_OUT[p] + u*no + io] = acc;
    }
  }
}

extern "C" void kernel_launch(void* const* d_in, const int* in_sizes, int n_in,
                              void* d_out, int out_size, void* d_ws, size_t ws_size,
                              hipStream_t stream){
  const float* x1 = (const float*)d_in[0];
  const float* x2 = (const float*)d_in[1];
  float* out = (float*)d_out;
  const int batch = in_sizes[0] / 576;

  float* cg = (float*)d_ws;                       // 1000 floats
  float* M  = (float*)((char*)d_ws + 4096);       // batch*270 floats
  const size_t need = 4096 + (size_t)batch * M_TOT * sizeof(float);

  cg_init<<<NP, 256, 0, stream>>>(cg);
  if (ws_size >= need){
    const int total = batch * M_TOT;
    m_kernel<<<(total + 255)/256, 256, 0, stream>>>(x2, cg, M, batch);
    tp_bounce<<<(batch + 3)/4, 256, 0, stream>>>(x1, M, out, batch);
  } else {
    tp_fallback<<<batch, 64, 0, stream>>>(x1, x2, cg, out);
  }
}